// Round 3
// baseline (236.272 us; speedup 1.0000x reference)
//
#include <hip/hip_runtime.h>
#include <math.h>

#define BB   4
#define HH   16
#define NN   4096
#define DD   64
#define MM   256
#define TOPN 16
#define ROWS 32
#define NTILES (NN / ROWS)   // 128

// ---------------------------------------------------------------------------
// k_scores: per (b, 32-row n-tile, head-group), loop over hpb heads.
//   scores = (q * 2^-3) . ck^T, softmax over M=256, write probs,
//   accumulate importance in regs, dump per-head-group partial imp to ws.
// Thread layout: 4 waves; wave wv owns rows wv*8..wv*8+7; lane c owns cols
//   4c..4c+3. Microtile 8x4 = 32 FMA per d fed by ONE conflict-free
//   ds_read_b128 (ck, contiguous 1KB row) + 2 broadcast b128 (q).
// ck staged d-major in two 32-d chunks: ckT[32][256] 32KB + qT 8KB = 40KB.
// ---------------------------------------------------------------------------
__global__ __launch_bounds__(256)
void k_scores(const float* __restrict__ q, const float* __restrict__ ck,
              float* __restrict__ out_scores, float* __restrict__ imp_out,
              int hpb) {
  __shared__ float ckT[32][MM];   // [dd][m], one 32-d chunk, 32 KB
  __shared__ float qT[DD][ROWS];  // [d][row], 8 KB

  const int bx   = blockIdx.x;
  const int hg   = blockIdx.y;
  const int b    = bx / NTILES;
  const int n0   = (bx % NTILES) * ROWS;
  const int tid  = threadIdx.x;
  const int lane = tid & 63;
  const int r0   = (tid >> 6) * 8;  // wave's first row

  float imp[8][4];
#pragma unroll
  for (int i = 0; i < 8; i++)
#pragma unroll
    for (int j = 0; j < 4; j++) imp[i][j] = 0.0f;

  const int h_end = (hg + 1) * hpb;
  for (int h = hg * hpb; h < h_end; ++h) {
    float acc[8][4];
#pragma unroll
    for (int i = 0; i < 8; i++)
#pragma unroll
      for (int j = 0; j < 4; j++) acc[i][j] = 0.0f;

#pragma unroll
    for (int kc = 0; kc < 2; ++kc) {
      __syncthreads();  // previous chunk/head compute done

      {  // stage ck chunk kc: thread tid owns m=tid, 32 d's (128 B contiguous)
        const float* cp =
            ck + ((size_t)(b * HH + h) * MM + tid) * DD + kc * 32;
#pragma unroll
        for (int j = 0; j < 8; ++j) {
          const float4 a = *(const float4*)(cp + j * 4);
          // per ds_write: lanes write consecutive 4B -> conflict-free
          ckT[j * 4 + 0][tid] = a.x;
          ckT[j * 4 + 1][tid] = a.y;
          ckT[j * 4 + 2][tid] = a.z;
          ckT[j * 4 + 3][tid] = a.w;
        }
      }
      if (kc == 0) {  // stage qT once per head (pre-scaled by D^-1/2 = 2^-3)
        const int row = tid & 31;
        const int dch = tid >> 5;
        const float* qp =
            q + ((size_t)(b * HH + h) * NN + n0 + row) * DD + dch * 8;
        const float4 a0 = *(const float4*)(qp);
        const float4 a1 = *(const float4*)(qp + 4);
        const float s = 0.125f;
        qT[dch * 8 + 0][row] = a0.x * s;
        qT[dch * 8 + 1][row] = a0.y * s;
        qT[dch * 8 + 2][row] = a0.z * s;
        qT[dch * 8 + 3][row] = a0.w * s;
        qT[dch * 8 + 4][row] = a1.x * s;
        qT[dch * 8 + 5][row] = a1.y * s;
        qT[dch * 8 + 6][row] = a1.z * s;
        qT[dch * 8 + 7][row] = a1.w * s;
      }
      __syncthreads();

#pragma unroll 8
      for (int dd = 0; dd < 32; ++dd) {
        const float4 cv = *(const float4*)&ckT[dd][lane * 4];
        const float4 q0 = *(const float4*)&qT[kc * 32 + dd][r0];
        const float4 q1 = *(const float4*)&qT[kc * 32 + dd][r0 + 4];
        acc[0][0] = fmaf(q0.x, cv.x, acc[0][0]);
        acc[0][1] = fmaf(q0.x, cv.y, acc[0][1]);
        acc[0][2] = fmaf(q0.x, cv.z, acc[0][2]);
        acc[0][3] = fmaf(q0.x, cv.w, acc[0][3]);
        acc[1][0] = fmaf(q0.y, cv.x, acc[1][0]);
        acc[1][1] = fmaf(q0.y, cv.y, acc[1][1]);
        acc[1][2] = fmaf(q0.y, cv.z, acc[1][2]);
        acc[1][3] = fmaf(q0.y, cv.w, acc[1][3]);
        acc[2][0] = fmaf(q0.z, cv.x, acc[2][0]);
        acc[2][1] = fmaf(q0.z, cv.y, acc[2][1]);
        acc[2][2] = fmaf(q0.z, cv.z, acc[2][2]);
        acc[2][3] = fmaf(q0.z, cv.w, acc[2][3]);
        acc[3][0] = fmaf(q0.w, cv.x, acc[3][0]);
        acc[3][1] = fmaf(q0.w, cv.y, acc[3][1]);
        acc[3][2] = fmaf(q0.w, cv.z, acc[3][2]);
        acc[3][3] = fmaf(q0.w, cv.w, acc[3][3]);
        acc[4][0] = fmaf(q1.x, cv.x, acc[4][0]);
        acc[4][1] = fmaf(q1.x, cv.y, acc[4][1]);
        acc[4][2] = fmaf(q1.x, cv.z, acc[4][2]);
        acc[4][3] = fmaf(q1.x, cv.w, acc[4][3]);
        acc[5][0] = fmaf(q1.y, cv.x, acc[5][0]);
        acc[5][1] = fmaf(q1.y, cv.y, acc[5][1]);
        acc[5][2] = fmaf(q1.y, cv.z, acc[5][2]);
        acc[5][3] = fmaf(q1.y, cv.w, acc[5][3]);
        acc[6][0] = fmaf(q1.z, cv.x, acc[6][0]);
        acc[6][1] = fmaf(q1.z, cv.y, acc[6][1]);
        acc[6][2] = fmaf(q1.z, cv.z, acc[6][2]);
        acc[6][3] = fmaf(q1.z, cv.w, acc[6][3]);
        acc[7][0] = fmaf(q1.w, cv.x, acc[7][0]);
        acc[7][1] = fmaf(q1.w, cv.y, acc[7][1]);
        acc[7][2] = fmaf(q1.w, cv.z, acc[7][2]);
        acc[7][3] = fmaf(q1.w, cv.w, acc[7][3]);
      }
    }

    // ---- softmax: each wave reduces its 8 rows across its 64 lanes ----
#pragma unroll
    for (int i = 0; i < 8; i++) {
      float mx = fmaxf(fmaxf(acc[i][0], acc[i][1]), fmaxf(acc[i][2], acc[i][3]));
#pragma unroll
      for (int off = 1; off < 64; off <<= 1)
        mx = fmaxf(mx, __shfl_xor(mx, off, 64));

      float sum = 0.0f;
#pragma unroll
      for (int j = 0; j < 4; j++) {
        acc[i][j] = __expf(acc[i][j] - mx);
        sum += acc[i][j];
      }
#pragma unroll
      for (int off = 1; off < 64; off <<= 1) sum += __shfl_xor(sum, off, 64);

      const float inv = 1.0f / sum;
#pragma unroll
      for (int j = 0; j < 4; j++) {
        acc[i][j] *= inv;
        imp[i][j] += acc[i][j];
      }

      float* op =
          out_scores + ((size_t)(b * HH + h) * NN + n0 + r0 + i) * MM;
      *(float4*)(op + lane * 4) =
          make_float4(acc[i][0], acc[i][1], acc[i][2], acc[i][3]);
    }
  }

  if (imp_out != nullptr) {
    float* base = imp_out + (size_t)hg * BB * NN * MM;
#pragma unroll
    for (int i = 0; i < 8; i++) {
      float* op = base + ((size_t)b * NN + n0 + r0 + i) * MM;
      *(float4*)(op + lane * 4) =
          make_float4(imp[i][0], imp[i][1], imp[i][2], imp[i][3]);
    }
  }
}

// ---------------------------------------------------------------------------
// Top-k: one 64-lane wave per (b,n) row; 16 argmax iterations with
// lower-index tiebreak == jax.lax.top_k stable semantics.
// ---------------------------------------------------------------------------
__device__ __forceinline__ void topk_row(float vals[4], int lane, int b, int n,
                                         float* __restrict__ out_idx) {
  int keep = 0;
#pragma unroll
  for (int it = 0; it < TOPN; ++it) {
    float bv = vals[0];
    int bi = lane * 4;
#pragma unroll
    for (int j = 1; j < 4; j++) {
      if (vals[j] > bv) { bv = vals[j]; bi = lane * 4 + j; }
    }
    for (int off = 1; off < 64; off <<= 1) {
      const float ov = __shfl_xor(bv, off, 64);
      const int oi = __shfl_xor(bi, off, 64);
      if (ov > bv || (ov == bv && oi < bi)) { bv = ov; bi = oi; }
    }
    if (lane == it) keep = bi;
    if ((bi >> 2) == lane) vals[bi & 3] = -INFINITY;
  }
  if (lane < TOPN)
    out_idx[((size_t)b * NN + n) * TOPN + lane] = (float)keep;
}

__global__ __launch_bounds__(256)
void k_topk(const float* __restrict__ imp, float* __restrict__ out_idx,
            int nsplit) {
  const int wave = blockIdx.x * 4 + (threadIdx.x >> 6);
  const int lane = threadIdx.x & 63;
  const int b = wave >> 12;
  const int n = wave & (NN - 1);
  float vals[4] = {0.f, 0.f, 0.f, 0.f};
  for (int s = 0; s < nsplit; ++s) {
    const float4 v = *(const float4*)(imp + (size_t)s * BB * NN * MM +
                                      ((size_t)b * NN + n) * MM + lane * 4);
    vals[0] += v.x; vals[1] += v.y; vals[2] += v.z; vals[3] += v.w;
  }
  topk_row(vals, lane, b, n, out_idx);
}

__global__ __launch_bounds__(256)
void k_topk_from_scores(const float* __restrict__ scores,
                        float* __restrict__ out_idx) {
  const int wave = blockIdx.x * 4 + (threadIdx.x >> 6);
  const int lane = threadIdx.x & 63;
  const int b = wave >> 12;
  const int n = wave & (NN - 1);
  float vals[4] = {0.f, 0.f, 0.f, 0.f};
  for (int h = 0; h < HH; ++h) {
    const float4 s = *(const float4*)(scores +
                                      (((size_t)(b * HH + h) * NN) + n) * MM +
                                      lane * 4);
    vals[0] += s.x; vals[1] += s.y; vals[2] += s.z; vals[3] += s.w;
  }
  topk_row(vals, lane, b, n, out_idx);
}

extern "C" void kernel_launch(void* const* d_in, const int* in_sizes, int n_in,
                              void* d_out, int out_size, void* d_ws,
                              size_t ws_size, hipStream_t stream) {
  const float* q  = (const float*)d_in[0];
  const float* ck = (const float*)d_in[1];
  // d_in[2] (k) and d_in[3] (v) unused by the reference output.

  float* out        = (float*)d_out;
  float* out_idx    = out;                           // B*N*16 floats
  float* out_scores = out + (size_t)BB * NN * TOPN;  // B*H*N*M floats

  const size_t one = (size_t)BB * NN * MM * sizeof(float);  // 16.78 MB

  int hsplit;
  float* imp;
  if (ws_size >= 2 * one) { hsplit = 2; imp = (float*)d_ws; }
  else if (ws_size >= one) { hsplit = 1; imp = (float*)d_ws; }
  else { hsplit = 1; imp = nullptr; }

  dim3 grid(BB * NTILES, hsplit);
  k_scores<<<grid, 256, 0, stream>>>(q, ck, out_scores, imp, HH / hsplit);

  if (imp != nullptr) {
    k_topk<<<(BB * NN) / 4, 256, 0, stream>>>(imp, out_idx, hsplit);
  } else {
    k_topk_from_scores<<<(BB * NN) / 4, 256, 0, stream>>>(out_scores, out_idx);
  }
}

// Round 4
// 196.887 us; speedup vs baseline: 1.2000x; 1.2000x over previous
//
#include <hip/hip_runtime.h>
#include <math.h>

#define BB   4
#define HH   16
#define NN   4096
#define DD   64
#define MM   256
#define TOPN 16
#define ROWS 32
#define NTILES (NN / ROWS)   // 128

typedef float f4v __attribute__((ext_vector_type(4)));

__device__ __forceinline__ void nt_store4(float* p, float a, float b, float c,
                                          float d) {
  f4v v = {a, b, c, d};
  __builtin_nontemporal_store(v, (f4v*)p);
}

// ---------------------------------------------------------------------------
// k_scores: per (b, 32-row n-tile, head-group), loop over hpb heads.
//   scores = (q * 2^-3) . ck^T, softmax over M=256, write probs (nt-store),
//   accumulate importance in regs, dump per-head-group partial imp to ws.
// Thread layout: 4 waves; wave wv owns rows wv*8..wv*8+7; lane c owns cols
//   4c..4c+3. Microtile 8x4 = 32 FMA per d fed by ONE conflict-free
//   ds_read_b128 (ck, contiguous 1KB row) + 2 broadcast b128 (q).
// ck staged d-major in two 32-d chunks: ckT[32][256] 32KB + qT 8KB = 40KB.
// __launch_bounds__(256,4): cap unified VGPR+AGPR at 128/thread so acc+imp
// stay in arch VGPRs (R3 regression: compiler spilled to AGPRs, occ 25%).
// ---------------------------------------------------------------------------
__global__ __launch_bounds__(256, 4)
void k_scores(const float* __restrict__ q, const float* __restrict__ ck,
              float* __restrict__ out_scores, float* __restrict__ imp_out,
              int hpb) {
  __shared__ float ckT[32][MM];   // [dd][m], one 32-d chunk, 32 KB
  __shared__ float qT[DD][ROWS];  // [d][row], 8 KB

  const int bx   = blockIdx.x;
  const int hg   = blockIdx.y;
  const int b    = bx / NTILES;
  const int n0   = (bx % NTILES) * ROWS;
  const int tid  = threadIdx.x;
  const int lane = tid & 63;
  const int r0   = (tid >> 6) * 8;  // wave's first row

  float imp[8][4];
#pragma unroll
  for (int i = 0; i < 8; i++)
#pragma unroll
    for (int j = 0; j < 4; j++) imp[i][j] = 0.0f;

  const int h_end = (hg + 1) * hpb;
  for (int h = hg * hpb; h < h_end; ++h) {
    float acc[8][4];
#pragma unroll
    for (int i = 0; i < 8; i++)
#pragma unroll
      for (int j = 0; j < 4; j++) acc[i][j] = 0.0f;

#pragma unroll
    for (int kc = 0; kc < 2; ++kc) {
      __syncthreads();  // previous chunk/head compute done

      {  // stage ck chunk kc: thread tid owns m=tid, 32 d's (128 B contiguous)
        const float* cp =
            ck + ((size_t)(b * HH + h) * MM + tid) * DD + kc * 32;
#pragma unroll
        for (int j = 0; j < 8; ++j) {
          const float4 a = *(const float4*)(cp + j * 4);
          // per ds_write: lanes write consecutive 4B -> conflict-free
          ckT[j * 4 + 0][tid] = a.x;
          ckT[j * 4 + 1][tid] = a.y;
          ckT[j * 4 + 2][tid] = a.z;
          ckT[j * 4 + 3][tid] = a.w;
        }
      }
      if (kc == 0) {  // stage qT once per head (pre-scaled by D^-1/2 = 2^-3)
        const int row = tid & 31;
        const int dch = tid >> 5;
        const float* qp =
            q + ((size_t)(b * HH + h) * NN + n0 + row) * DD + dch * 8;
        const float4 a0 = *(const float4*)(qp);
        const float4 a1 = *(const float4*)(qp + 4);
        const float s = 0.125f;
        qT[dch * 8 + 0][row] = a0.x * s;
        qT[dch * 8 + 1][row] = a0.y * s;
        qT[dch * 8 + 2][row] = a0.z * s;
        qT[dch * 8 + 3][row] = a0.w * s;
        qT[dch * 8 + 4][row] = a1.x * s;
        qT[dch * 8 + 5][row] = a1.y * s;
        qT[dch * 8 + 6][row] = a1.z * s;
        qT[dch * 8 + 7][row] = a1.w * s;
      }
      __syncthreads();

#pragma unroll 2
      for (int dd = 0; dd < 32; ++dd) {
        const float4 cv = *(const float4*)&ckT[dd][lane * 4];
        const float4 q0 = *(const float4*)&qT[kc * 32 + dd][r0];
        const float4 q1 = *(const float4*)&qT[kc * 32 + dd][r0 + 4];
        acc[0][0] = fmaf(q0.x, cv.x, acc[0][0]);
        acc[0][1] = fmaf(q0.x, cv.y, acc[0][1]);
        acc[0][2] = fmaf(q0.x, cv.z, acc[0][2]);
        acc[0][3] = fmaf(q0.x, cv.w, acc[0][3]);
        acc[1][0] = fmaf(q0.y, cv.x, acc[1][0]);
        acc[1][1] = fmaf(q0.y, cv.y, acc[1][1]);
        acc[1][2] = fmaf(q0.y, cv.z, acc[1][2]);
        acc[1][3] = fmaf(q0.y, cv.w, acc[1][3]);
        acc[2][0] = fmaf(q0.z, cv.x, acc[2][0]);
        acc[2][1] = fmaf(q0.z, cv.y, acc[2][1]);
        acc[2][2] = fmaf(q0.z, cv.z, acc[2][2]);
        acc[2][3] = fmaf(q0.z, cv.w, acc[2][3]);
        acc[3][0] = fmaf(q0.w, cv.x, acc[3][0]);
        acc[3][1] = fmaf(q0.w, cv.y, acc[3][1]);
        acc[3][2] = fmaf(q0.w, cv.z, acc[3][2]);
        acc[3][3] = fmaf(q0.w, cv.w, acc[3][3]);
        acc[4][0] = fmaf(q1.x, cv.x, acc[4][0]);
        acc[4][1] = fmaf(q1.x, cv.y, acc[4][1]);
        acc[4][2] = fmaf(q1.x, cv.z, acc[4][2]);
        acc[4][3] = fmaf(q1.x, cv.w, acc[4][3]);
        acc[5][0] = fmaf(q1.y, cv.x, acc[5][0]);
        acc[5][1] = fmaf(q1.y, cv.y, acc[5][1]);
        acc[5][2] = fmaf(q1.y, cv.z, acc[5][2]);
        acc[5][3] = fmaf(q1.y, cv.w, acc[5][3]);
        acc[6][0] = fmaf(q1.z, cv.x, acc[6][0]);
        acc[6][1] = fmaf(q1.z, cv.y, acc[6][1]);
        acc[6][2] = fmaf(q1.z, cv.z, acc[6][2]);
        acc[6][3] = fmaf(q1.z, cv.w, acc[6][3]);
        acc[7][0] = fmaf(q1.w, cv.x, acc[7][0]);
        acc[7][1] = fmaf(q1.w, cv.y, acc[7][1]);
        acc[7][2] = fmaf(q1.w, cv.z, acc[7][2]);
        acc[7][3] = fmaf(q1.w, cv.w, acc[7][3]);
      }
    }

    // ---- softmax: each wave reduces its 8 rows across its 64 lanes ----
#pragma unroll
    for (int i = 0; i < 8; i++) {
      float mx = fmaxf(fmaxf(acc[i][0], acc[i][1]), fmaxf(acc[i][2], acc[i][3]));
#pragma unroll
      for (int off = 1; off < 64; off <<= 1)
        mx = fmaxf(mx, __shfl_xor(mx, off, 64));

      float sum = 0.0f;
#pragma unroll
      for (int j = 0; j < 4; j++) {
        acc[i][j] = __expf(acc[i][j] - mx);
        sum += acc[i][j];
      }
#pragma unroll
      for (int off = 1; off < 64; off <<= 1) sum += __shfl_xor(sum, off, 64);

      const float inv = 1.0f / sum;
#pragma unroll
      for (int j = 0; j < 4; j++) {
        acc[i][j] *= inv;
        imp[i][j] += acc[i][j];
      }

      float* op =
          out_scores + ((size_t)(b * HH + h) * NN + n0 + r0 + i) * MM;
      // probs are written once and never re-read: bypass L2 (keep ck/q hot)
      nt_store4(op + lane * 4, acc[i][0], acc[i][1], acc[i][2], acc[i][3]);
    }
  }

  if (imp_out != nullptr) {
    float* base = imp_out + (size_t)hg * BB * NN * MM;
#pragma unroll
    for (int i = 0; i < 8; i++) {
      float* op = base + ((size_t)b * NN + n0 + r0 + i) * MM;
      *(float4*)(op + lane * 4) =
          make_float4(imp[i][0], imp[i][1], imp[i][2], imp[i][3]);
    }
  }
}

// ---------------------------------------------------------------------------
// Top-k: one 64-lane wave per (b,n) row; 16 argmax iterations with
// lower-index tiebreak == jax.lax.top_k stable semantics.
// ---------------------------------------------------------------------------
__device__ __forceinline__ void topk_row(float vals[4], int lane, int b, int n,
                                         float* __restrict__ out_idx) {
  int keep = 0;
#pragma unroll
  for (int it = 0; it < TOPN; ++it) {
    float bv = vals[0];
    int bi = lane * 4;
#pragma unroll
    for (int j = 1; j < 4; j++) {
      if (vals[j] > bv) { bv = vals[j]; bi = lane * 4 + j; }
    }
    for (int off = 1; off < 64; off <<= 1) {
      const float ov = __shfl_xor(bv, off, 64);
      const int oi = __shfl_xor(bi, off, 64);
      if (ov > bv || (ov == bv && oi < bi)) { bv = ov; bi = oi; }
    }
    if (lane == it) keep = bi;
    if ((bi >> 2) == lane) vals[bi & 3] = -INFINITY;
  }
  if (lane < TOPN)
    out_idx[((size_t)b * NN + n) * TOPN + lane] = (float)keep;
}

__global__ __launch_bounds__(256)
void k_topk(const float* __restrict__ imp, float* __restrict__ out_idx,
            int nsplit) {
  const int wave = blockIdx.x * 4 + (threadIdx.x >> 6);
  const int lane = threadIdx.x & 63;
  const int b = wave >> 12;
  const int n = wave & (NN - 1);
  float vals[4] = {0.f, 0.f, 0.f, 0.f};
  for (int s = 0; s < nsplit; ++s) {
    const float4 v = *(const float4*)(imp + (size_t)s * BB * NN * MM +
                                      ((size_t)b * NN + n) * MM + lane * 4);
    vals[0] += v.x; vals[1] += v.y; vals[2] += v.z; vals[3] += v.w;
  }
  topk_row(vals, lane, b, n, out_idx);
}

__global__ __launch_bounds__(256)
void k_topk_from_scores(const float* __restrict__ scores,
                        float* __restrict__ out_idx) {
  const int wave = blockIdx.x * 4 + (threadIdx.x >> 6);
  const int lane = threadIdx.x & 63;
  const int b = wave >> 12;
  const int n = wave & (NN - 1);
  float vals[4] = {0.f, 0.f, 0.f, 0.f};
  for (int h = 0; h < HH; ++h) {
    const float4 s = *(const float4*)(scores +
                                      (((size_t)(b * HH + h) * NN) + n) * MM +
                                      lane * 4);
    vals[0] += s.x; vals[1] += s.y; vals[2] += s.z; vals[3] += s.w;
  }
  topk_row(vals, lane, b, n, out_idx);
}

extern "C" void kernel_launch(void* const* d_in, const int* in_sizes, int n_in,
                              void* d_out, int out_size, void* d_ws,
                              size_t ws_size, hipStream_t stream) {
  const float* q  = (const float*)d_in[0];
  const float* ck = (const float*)d_in[1];
  // d_in[2] (k) and d_in[3] (v) unused by the reference output.

  float* out        = (float*)d_out;
  float* out_idx    = out;                           // B*N*16 floats
  float* out_scores = out + (size_t)BB * NN * TOPN;  // B*H*N*M floats

  const size_t one = (size_t)BB * NN * MM * sizeof(float);  // 16.78 MB

  int hsplit;
  float* imp;
  if (ws_size >= 2 * one) { hsplit = 2; imp = (float*)d_ws; }
  else if (ws_size >= one) { hsplit = 1; imp = (float*)d_ws; }
  else { hsplit = 1; imp = nullptr; }

  dim3 grid(BB * NTILES, hsplit);
  k_scores<<<grid, 256, 0, stream>>>(q, ck, out_scores, imp, HH / hsplit);

  if (imp != nullptr) {
    k_topk<<<(BB * NN) / 4, 256, 0, stream>>>(imp, out_idx, hsplit);
  } else {
    k_topk_from_scores<<<(BB * NN) / 4, 256, 0, stream>>>(out_scores, out_idx);
  }
}